// Round 10
// baseline (1593.465 us; speedup 1.0000x reference)
//
#include <hip/hip_runtime.h>
#include <hip/hip_bf16.h>

typedef __hip_bfloat16 bf16;
typedef __attribute__((ext_vector_type(8))) short short8v;
typedef __attribute__((ext_vector_type(4))) float float4v;

#define NCONS 50000
#define NVARS 50000
#define NEDGE 600000

__device__ __forceinline__ float b2f(const bf16 v){ return __bfloat162float(v); }
__device__ __forceinline__ float shflf(float v, int lane){ return __shfl(v, lane, 64); }
__device__ __forceinline__ unsigned short f2b(float v){
  return __builtin_bit_cast(unsigned short, __float2bfloat16(v));
}

// ---- input-dtype sniffer (bf16 pairs vs f32) ----
__global__ void detect_k(const unsigned int* __restrict__ x, int* __restrict__ mode){
  int t = threadIdx.x;
  int hits = 0;
  for (int i=0;i<4;++i){
    unsigned w = x[t*4+i];
    unsigned e = (w>>7)&0xFFu;
    if (e >= 0x70u && e <= 0x8Fu) hits++;
  }
  for (int off=32; off>0; off>>=1) hits += __shfl_down(hits, off);
  if (t==0) *mode = (hits > 128) ? 1 : 0;
}

// ---- convert ALL 36 float inputs to f32 workspace in one launch ----
struct CvtArgs { const void* p[36]; int ofs[37]; };
__global__ void convert_all_k(CvtArgs a, float* __restrict__ dst, const int* __restrict__ mode){
  int m = *mode;
  int i = blockIdx.x*blockDim.x + threadIdx.x;
  int stride = gridDim.x*blockDim.x;
  int total = a.ofs[36];
  for (; i<total; i+=stride){
    int s = 0;
#pragma unroll
    for (int k=1;k<36;++k) s += (i >= a.ofs[k]) ? 1 : 0;
    int off = i - a.ofs[s];
    float v;
    if (m) v = b2f(((const bf16*)a.p[s])[off]);
    else   v = ((const float*)a.p[s])[off];
    dst[i] = v;
  }
}

__global__ void zero_k(float* __restrict__ p, int n){
  int i = blockIdx.x*blockDim.x + threadIdx.x;
  int stride = gridDim.x*blockDim.x;
  for (; i<n; i+=stride) p[i] = 0.f;
}

// ---- CSR build: histogram, single-block scan, scatter ----
__global__ void hist_k(const int* __restrict__ ei, int* __restrict__ cntc, int* __restrict__ cntv){
  int i = blockIdx.x*blockDim.x + threadIdx.x;
  int stride = gridDim.x*blockDim.x;
  for (; i<2*NEDGE; i+=stride){
    int id = ei[i];
    if (i < NEDGE) atomicAdd(&cntc[id], 1);
    else           atomicAdd(&cntv[id], 1);
  }
}

__global__ void __launch_bounds__(1024) scan_k(const int* __restrict__ cnt, int* __restrict__ offs,
                                               int* __restrict__ cur, int n){
  __shared__ int part[1024];
  int t = threadIdx.x;
  int chunk = (n + 1023) >> 10;
  int b = t*chunk;
  int e = b + chunk; if (e > n) e = n;
  int s = 0;
  for (int i=b; i<e; ++i) s += cnt[i];
  part[t] = s;
  __syncthreads();
  for (int off=1; off<1024; off<<=1){
    int v = (t >= off) ? part[t-off] : 0;
    __syncthreads();
    part[t] += v;
    __syncthreads();
  }
  int run = (t==0) ? 0 : part[t-1];
  for (int i=b; i<e; ++i){
    int c = cnt[i];
    offs[i] = run; cur[i] = run;
    run += c;
  }
  if (t==1023) offs[n] = part[1023];
}

__global__ void scat_k(const int* __restrict__ ei, int* __restrict__ curc, int* __restrict__ curv,
                       int* __restrict__ permc, int* __restrict__ permv){
  int i = blockIdx.x*blockDim.x + threadIdx.x;
  int stride = gridDim.x*blockDim.x;
  for (; i<2*NEDGE; i+=stride){
    int id = ei[i];
    if (i < NEDGE){ int p = atomicAdd(&curc[id],1); permc[p] = i; }
    else          { int p = atomicAdd(&curv[id],1); permv[p] = i - NEDGE; }
  }
}

// ---- per-column sums / sumsq for BN folding ----
__global__ void col_stats_k(const float* __restrict__ x, int rows, int cols, float* __restrict__ sums){
  int tid = blockIdx.x*blockDim.x + threadIdx.x;
  int stride = gridDim.x*blockDim.x;
  float s[5], ss[5];
  for (int c=0;c<5;++c){ s[c]=0.f; ss[c]=0.f; }
  for (int r=tid; r<rows; r+=stride){
    for (int c=0;c<cols;++c){
      float v = x[r*cols+c];
      s[c]+=v; ss[c]+=v*v;
    }
  }
  for (int c=0;c<cols;++c){
    float a=s[c], b=ss[c];
    for (int off=32; off>0; off>>=1){ a+=__shfl_down(a,off); b+=__shfl_down(b,off); }
    if ((threadIdx.x & 63)==0){ atomicAdd(&sums[c],a); atomicAdd(&sums[cols+c],b); }
  }
}

// stats float layout in ST (floats): see round-5 comment (unchanged)
__global__ void fin_input_k(float* __restrict__ st,
                            const float* __restrict__ cw, const float* __restrict__ cb,
                            const float* __restrict__ vw, const float* __restrict__ vb,
                            const float* __restrict__ ew, const float* __restrict__ eb){
  int t = threadIdx.x;
  if (t < 3){
    float m = st[t]/(float)NCONS, q = st[3+t]/(float)NCONS;
    float A = rsqrtf(fmaxf(q - m*m, 0.f) + 1e-5f)*cw[t];
    st[18+t] = A; st[21+t] = cb[t] - m*A;
  } else if (t < 8){
    int c = t-3;
    float m = st[6+c]/(float)NVARS, q = st[11+c]/(float)NVARS;
    float A = rsqrtf(fmaxf(q - m*m, 0.f) + 1e-5f)*vw[c];
    st[24+c] = A; st[29+c] = vb[c] - m*A;
  } else if (t == 8){
    float m = st[16]/(float)NEDGE, q = st[17]/(float)NEDGE;
    float A = rsqrtf(fmaxf(q - m*m, 0.f) + 1e-5f)*ew[0];
    st[34] = A; st[35] = eb[0] - m*A;
  }
}

// ---- embedding: relu(relu(BN(x)@W1+b1)@W2+b2), block(64)=one node ----
__global__ void embed_k(const float* __restrict__ x, int cin,
                        const float* __restrict__ pA, const float* __restrict__ pB,
                        const float* __restrict__ W1, const float* __restrict__ b1,
                        const float* __restrict__ W2, const float* __restrict__ b2,
                        bf16* __restrict__ out, int nn){
  int n = blockIdx.x; if (n>=nn) return;
  int t = threadIdx.x;
  float acc = b1[t];
  for (int k=0;k<cin;++k){
    float xb = x[n*cin+k]*pA[k] + pB[k];
    acc += xb*W1[k*64+t];
  }
  float h1 = fmaxf(acc, 0.f);
  float acc2 = b2[t];
#pragma unroll
  for (int j=0;j<64;++j) acc2 += shflf(h1,j)*W2[j*64+t];
  out[n*64+t] = __float2bfloat16(fmaxf(acc2, 0.f));
}

// ---- all 16 conv-weight fragment jobs in one launch ----
__global__ void frag_all_k(const float* __restrict__ fmW1, const float* __restrict__ fmW2,
                           const float* __restrict__ omW1, const float* __restrict__ omW2,
                           unsigned short* __restrict__ W1Fb, unsigned short* __restrict__ W2Fb,
                           unsigned short* __restrict__ OW1Fb, unsigned short* __restrict__ OW2Fb){
  int i = blockIdx.x*blockDim.x + threadIdx.x;
  if (i >= 4*24576) return;
  int l = i / 24576, r = i % 24576;
  const float* src; unsigned short* dst; int e; int skip;
  if (r < 8192){       src = fmW1 + (size_t)l*129*64; dst = W1Fb  + l*8192; e = r;       skip = 64; }
  else if (r < 12288){ src = fmW2 + (size_t)l*64*64;  dst = W2Fb  + l*4096; e = r-8192;  skip = -1; }
  else if (r < 20480){ src = omW1 + (size_t)l*128*64; dst = OW1Fb + l*8192; e = r-12288; skip = -1; }
  else {               src = omW2 + (size_t)l*64*64;  dst = OW2Fb + l*4096; e = r-20480; skip = -1; }
  int j = e & 7, lane = (e>>3)&63, n = (e>>9)&3, kc = e>>11;
  int k = kc*32 + (lane>>4)*8 + j;
  int col = n*16 + (lane&15);
  int srcrow = (skip>=0 && k>=skip) ? k+1 : k;
  dst[e] = f2b(src[srcrow*64 + col]);
}

// ---- hi/lo fragmenter for final-MLP weights ----
__global__ void frag2_k(const float* __restrict__ Wsrc, unsigned short* __restrict__ Whi,
                        unsigned short* __restrict__ Wlo, int ntiles, int ncols, int tot){
  int i = blockIdx.x*blockDim.x + threadIdx.x;
  if (i>=tot) return;
  int j = i & 7, lane = (i>>3)&63, rem = i>>9;
  int nt = rem % ntiles, kc = rem / ntiles;
  int k = kc*32 + (lane>>4)*8 + j;
  int col = nt*16 + (lane&15);
  float w = Wsrc[k*ncols + col];
  unsigned short hi = f2b(w);
  float rec = __builtin_bit_cast(float, (unsigned int)hi << 16);
  Whi[i] = hi;
  Wlo[i] = f2b(w - rec);
}

// ---- CSR MFMA edge-message kernel: ONE WAVE PER DST NODE, no atomics.
// right-part of h1 computed once per node; per 16-edge tile only left/ef parts;
// per-edge messages summed in registers; mean (+b2) stored directly. ----
__global__ void __launch_bounds__(256) msg_csr_k(
    const bf16* __restrict__ left, const bf16* __restrict__ right,
    const int* __restrict__ perm, const int* __restrict__ srcarr,
    const float* __restrict__ ea, const float* __restrict__ est,
    const int* __restrict__ offs,
    const unsigned short* __restrict__ W1F, const unsigned short* __restrict__ W2F,
    const float* __restrict__ b1, const float* __restrict__ w1e, const float* __restrict__ b2,
    float* __restrict__ agg, int nn)
{
  __shared__ __align__(16) unsigned short w1l[8192];
  __shared__ __align__(16) unsigned short w2l[4096];
  __shared__ __align__(16) unsigned short h1l[4][16*72];
  {
    const float4* s1 = (const float4*)W1F; float4* d1 = (float4*)w1l;
    for (int i=threadIdx.x; i<1024; i+=256) d1[i] = s1[i];
    const float4* s2 = (const float4*)W2F; float4* d2 = (float4*)w2l;
    for (int i=threadIdx.x; i<512; i+=256) d2[i] = s2[i];
  }
  __syncthreads();
  const short8v* W1v = (const short8v*)w1l;
  const short8v* W2v = (const short8v*)w2l;
  const unsigned short* rgt = (const unsigned short*)right;
  const unsigned short* lft = (const unsigned short*)left;
  int t = threadIdx.x & 63;
  int wv = threadIdx.x >> 6;
  int gw = (blockIdx.x*blockDim.x + threadIdx.x) >> 6;
  int nw = (gridDim.x*blockDim.x) >> 6;
  int r16 = t & 15, kg = t >> 4;
  float eA = est[0], eB = est[1];
  float bb1[4], we[4], bb2[4];
#pragma unroll
  for (int n=0;n<4;++n){ bb1[n]=b1[n*16+r16]; we[n]=w1e[n*16+r16]; bb2[n]=b2[n*16+r16]; }
  unsigned short* h1w = &h1l[wv][0];

  for (int node = gw; node < nn; node += nw){
    int beg = offs[node], end = offs[node+1];
    int deg = end - beg;
    float4v acc[4];
#pragma unroll
    for (int n=0;n<4;++n) acc[n] = (float4v){0.f,0.f,0.f,0.f};
    if (deg > 0){
      // right-part + b1 once per node (A rows all = right[node])
      short8v rr0 = *(const short8v*)(rgt + (size_t)node*64 + kg*8);
      short8v rr1 = *(const short8v*)(rgt + (size_t)node*64 + 32 + kg*8);
      float4v crt[4];
#pragma unroll
      for (int n=0;n<4;++n) crt[n] = (float4v){bb1[n],bb1[n],bb1[n],bb1[n]};
#pragma unroll
      for (int n=0;n<4;++n){
        crt[n] = __builtin_amdgcn_mfma_f32_16x16x32_bf16(rr0, W1v[(0+n)*64+t], crt[n], 0,0,0);
        crt[n] = __builtin_amdgcn_mfma_f32_16x16x32_bf16(rr1, W1v[(4+n)*64+t], crt[n], 0,0,0);
      }
      for (int base = beg; base < end; base += 16){
        int idx = base + r16;
        int e = perm[idx < end ? idx : beg];
        int sI = srcarr[e];
        float ef = ea[e]*eA + eB;
        short8v al0 = *(const short8v*)(lft + (size_t)sI*64 + kg*8);
        short8v al1 = *(const short8v*)(lft + (size_t)sI*64 + 32 + kg*8);
        float efr[4];
#pragma unroll
        for (int r=0;r<4;++r) efr[r] = shflf(ef, kg*4+r);
        float4v c[4];
#pragma unroll
        for (int n=0;n<4;++n){
#pragma unroll
          for (int r=0;r<4;++r) c[n][r] = crt[n][r] + efr[r]*we[n];
        }
#pragma unroll
        for (int n=0;n<4;++n){
          c[n] = __builtin_amdgcn_mfma_f32_16x16x32_bf16(al0, W1v[( 8+n)*64+t], c[n], 0,0,0);
          c[n] = __builtin_amdgcn_mfma_f32_16x16x32_bf16(al1, W1v[(12+n)*64+t], c[n], 0,0,0);
        }
#pragma unroll
        for (int n=0;n<4;++n){
#pragma unroll
          for (int r=0;r<4;++r)
            h1w[(kg*4+r)*72 + n*16 + r16] = f2b(fmaxf(c[n][r], 0.f));
        }
        asm volatile("s_waitcnt lgkmcnt(0)" ::: "memory");
        short8v a20 = *(const short8v*)(h1w + r16*72 + kg*8);
        short8v a21 = *(const short8v*)(h1w + r16*72 + 32 + kg*8);
        float4v d[4];
#pragma unroll
        for (int n=0;n<4;++n) d[n] = (float4v){0.f,0.f,0.f,0.f};
#pragma unroll
        for (int n=0;n<4;++n){
          d[n] = __builtin_amdgcn_mfma_f32_16x16x32_bf16(a20, W2v[(0+n)*64+t], d[n], 0,0,0);
          d[n] = __builtin_amdgcn_mfma_f32_16x16x32_bf16(a21, W2v[(4+n)*64+t], d[n], 0,0,0);
        }
        // masked accumulate: row kg*4+r is edge base+kg*4+r
#pragma unroll
        for (int r=0;r<4;++r){
          float mrow = (base + kg*4 + r < end) ? 1.f : 0.f;
#pragma unroll
          for (int n=0;n<4;++n) acc[n][r] += mrow * d[n][r];
        }
      }
    }
    // reduce rows: within-lane (4 regs) then across kg groups (lanes t^16, t^32)
    float tot[4];
#pragma unroll
    for (int n=0;n<4;++n){
      tot[n] = acc[n][0]+acc[n][1]+acc[n][2]+acc[n][3];
      tot[n] += __shfl_xor(tot[n], 16, 64);
      tot[n] += __shfl_xor(tot[n], 32, 64);
    }
    if (kg == 0){
      float inv = (deg>0) ? 1.f/(float)deg : 0.f;
#pragma unroll
      for (int n=0;n<4;++n)
        agg[(size_t)node*64 + n*16 + r16] = (deg>0) ? tot[n]*inv + bb2[n] : 0.f;
    }
  }
}

// ---- column stats of mean-agg (agg already holds the mean) ----
__global__ void agg_stats_k(const float* __restrict__ agg, float* __restrict__ slot, int nn){
  int c = threadIdx.x & 63;
  int w = (blockIdx.x*blockDim.x + threadIdx.x) >> 6;
  int nw = (gridDim.x*blockDim.x) >> 6;
  float s=0.f, ss=0.f;
  for (int n=w; n<nn; n+=nw){
    float v = agg[n*64+c];
    s += v; ss += v*v;
  }
  atomicAdd(&slot[c], s); atomicAdd(&slot[64+c], ss);
}

__global__ void fin_bn_k(float* __restrict__ slot, const float* __restrict__ w,
                         const float* __restrict__ b, float n){
  int c = threadIdx.x;
  float m = slot[c]/n, q = slot[64+c]/n;
  float rs = rsqrtf(fmaxf(q - m*m, 0.f) + 1e-5f) * w[c];
  slot[128+c] = rs;
  slot[192+c] = b[c] - m*rs;
}

// ---- MFMA node-output MLP: 16 nodes per wave-iteration. ----
__global__ void __launch_bounds__(256) node_mfma_k(
    const float* __restrict__ agg, const bf16* __restrict__ right,
    const float* __restrict__ slot,
    const unsigned short* __restrict__ W1F, const unsigned short* __restrict__ W2F,
    const float* __restrict__ b1, const float* __restrict__ b2,
    bf16* __restrict__ out, int nn)
{
  __shared__ __align__(16) unsigned short w1l[8192];
  __shared__ __align__(16) unsigned short w2l[4096];
  __shared__ __align__(16) unsigned short h1l[4][16*72];
  {
    const float4* s1 = (const float4*)W1F; float4* d1 = (float4*)w1l;
    for (int i=threadIdx.x; i<1024; i+=256) d1[i] = s1[i];
    const float4* s2 = (const float4*)W2F; float4* d2 = (float4*)w2l;
    for (int i=threadIdx.x; i<512; i+=256) d2[i] = s2[i];
  }
  __syncthreads();
  const short8v* W1v = (const short8v*)w1l;
  const short8v* W2v = (const short8v*)w2l;
  const unsigned short* rgt = (const unsigned short*)right;
  int t = threadIdx.x & 63;
  int wv = threadIdx.x >> 6;
  int gw = (blockIdx.x*blockDim.x + threadIdx.x) >> 6;
  int nw = (gridDim.x*blockDim.x) >> 6;
  int r16 = t & 15, kg = t >> 4;
  float pA0[8], pB0[8], pA1[8], pB1[8];
#pragma unroll
  for (int j=0;j<8;++j){
    pA0[j]=slot[128+kg*8+j]; pB0[j]=slot[192+kg*8+j];
    pA1[j]=slot[160+kg*8+j]; pB1[j]=slot[224+kg*8+j];
  }
  float bb1[4], bb2[4];
#pragma unroll
  for (int n=0;n<4;++n){ bb1[n]=b1[n*16+r16]; bb2[n]=b2[n*16+r16]; }
  unsigned short* h1w = &h1l[wv][0];

  for (int g = gw*16; g < nn; g += nw*16){
    int node = g + r16;
    const float* ag = agg + (size_t)node*64;
    float4 f0 = *(const float4*)(ag + kg*8);
    float4 f1 = *(const float4*)(ag + kg*8 + 4);
    float4 f2 = *(const float4*)(ag + 32 + kg*8);
    float4 f3 = *(const float4*)(ag + 32 + kg*8 + 4);
    float v0[8] = {f0.x,f0.y,f0.z,f0.w,f1.x,f1.y,f1.z,f1.w};
    float v1[8] = {f2.x,f2.y,f2.z,f2.w,f3.x,f3.y,f3.z,f3.w};
    short8v ap0, ap1;
#pragma unroll
    for (int j=0;j<8;++j){
      ((unsigned short*)&ap0)[j] = f2b(v0[j]*pA0[j] + pB0[j]);
      ((unsigned short*)&ap1)[j] = f2b(v1[j]*pA1[j] + pB1[j]);
    }
    short8v ar0 = *(const short8v*)(rgt + (size_t)node*64 + kg*8);
    short8v ar1 = *(const short8v*)(rgt + (size_t)node*64 + 32 + kg*8);
    float4v c[4];
#pragma unroll
    for (int n=0;n<4;++n) c[n] = (float4v){bb1[n],bb1[n],bb1[n],bb1[n]};
#pragma unroll
    for (int n=0;n<4;++n){
      c[n] = __builtin_amdgcn_mfma_f32_16x16x32_bf16(ap0, W1v[( 0+n)*64+t], c[n], 0,0,0);
      c[n] = __builtin_amdgcn_mfma_f32_16x16x32_bf16(ap1, W1v[( 4+n)*64+t], c[n], 0,0,0);
      c[n] = __builtin_amdgcn_mfma_f32_16x16x32_bf16(ar0, W1v[( 8+n)*64+t], c[n], 0,0,0);
      c[n] = __builtin_amdgcn_mfma_f32_16x16x32_bf16(ar1, W1v[(12+n)*64+t], c[n], 0,0,0);
    }
#pragma unroll
    for (int n=0;n<4;++n){
#pragma unroll
      for (int r=0;r<4;++r)
        h1w[(kg*4+r)*72 + n*16 + r16] = f2b(fmaxf(c[n][r], 0.f));
    }
    asm volatile("s_waitcnt lgkmcnt(0)" ::: "memory");
    short8v a20 = *(const short8v*)(h1w + r16*72 + kg*8);
    short8v a21 = *(const short8v*)(h1w + r16*72 + 32 + kg*8);
    float4v d[4];
#pragma unroll
    for (int n=0;n<4;++n) d[n] = (float4v){bb2[n],bb2[n],bb2[n],bb2[n]};
#pragma unroll
    for (int n=0;n<4;++n){
      d[n] = __builtin_amdgcn_mfma_f32_16x16x32_bf16(a20, W2v[(0+n)*64+t], d[n], 0,0,0);
      d[n] = __builtin_amdgcn_mfma_f32_16x16x32_bf16(a21, W2v[(4+n)*64+t], d[n], 0,0,0);
    }
    unsigned short* op = (unsigned short*)out;
#pragma unroll
    for (int r=0;r<4;++r){
      size_t base = (size_t)(g + kg*4 + r)*64 + r16;
#pragma unroll
      for (int n=0;n<4;++n) op[base + n*16] = f2b(d[n][r]);
    }
  }
}

// ---- graphnorm stats / finalize / apply ----
__global__ void gn_stats_k(const bf16* __restrict__ x, float* __restrict__ slot, int nn){
  int c = threadIdx.x & 63;
  int w = (blockIdx.x*blockDim.x + threadIdx.x) >> 6;
  int nw = (gridDim.x*blockDim.x) >> 6;
  float s=0.f, ss=0.f;
  for (int n=w;n<nn;n+=nw){ float v=b2f(x[n*64+c]); s+=v; ss+=v*v; }
  atomicAdd(&slot[c],s); atomicAdd(&slot[64+c],ss);
}

__global__ void fin_gn_k(float* __restrict__ slot, const float* __restrict__ w,
                         const float* __restrict__ b, const float* __restrict__ al, float n){
  int c = threadIdx.x;
  float m = slot[c]/n, q = slot[64+c]/n;
  float a = al[c];
  float var = q - 2.f*a*m*m + a*a*m*m;
  float A = rsqrtf(fmaxf(var, 0.f) + 1e-5f) * w[c];
  slot[128+c] = A;
  slot[192+c] = b[c] - a*m*A;
}

__global__ void affine_k(bf16* __restrict__ x, const float* __restrict__ slot, int nn){
  int i = blockIdx.x*blockDim.x + threadIdx.x;
  int stride = gridDim.x*blockDim.x;
  int tot = nn*64;
  for (; i<tot; i+=stride){
    int c = i & 63;
    x[i] = __float2bfloat16(b2f(x[i])*slot[128+c] + slot[192+c]);
  }
}

// ---- MFMA final MLP, race-free (one 16-node tile per wave, __syncthreads) ----
__global__ void __launch_bounds__(256) final_mfma_k(
    const bf16* __restrict__ vf0, const bf16* __restrict__ vf1, const bf16* __restrict__ vf2,
    const unsigned short* __restrict__ W1hi, const unsigned short* __restrict__ W1lo,
    const unsigned short* __restrict__ W2hi, const unsigned short* __restrict__ W2lo,
    const float* __restrict__ B1, const float* __restrict__ B2,
    const float* __restrict__ W3, const float* __restrict__ B3,
    void* __restrict__ out, int nn, const int* __restrict__ mode)
{
  __shared__ float h1l[4][16*260];
  const short8v* W1h = (const short8v*)W1hi;
  const short8v* W1l = (const short8v*)W1lo;
  const short8v* W2h = (const short8v*)W2hi;
  const short8v* W2l = (const short8v*)W2lo;
  const unsigned short* v0p = (const unsigned short*)vf0;
  const unsigned short* v1p = (const unsigned short*)vf1;
  const unsigned short* v2p = (const unsigned short*)vf2;
  int t = threadIdx.x & 63;
  int wv = threadIdx.x >> 6;
  int r16 = t & 15, kg = t >> 4;
  int tile = blockIdx.x*4 + wv;
  bool act = (tile*16 < nn);
  int g = act ? tile*16 : 0;
  float* h1w = &h1l[wv][0];
  float b2v[8], w3v[8];
#pragma unroll
  for (int n=0;n<8;++n){ b2v[n] = B2[n*16+r16]; w3v[n] = W3[n*16+r16]; }
  float bb3 = B3[0];
  int md = *mode;

  int node = g + r16;
  short8v A1[6];
  A1[0] = *(const short8v*)(v0p + (size_t)node*64 + kg*8);
  A1[1] = *(const short8v*)(v0p + (size_t)node*64 + 32 + kg*8);
  A1[2] = *(const short8v*)(v1p + (size_t)node*64 + kg*8);
  A1[3] = *(const short8v*)(v1p + (size_t)node*64 + 32 + kg*8);
  A1[4] = *(const short8v*)(v2p + (size_t)node*64 + kg*8);
  A1[5] = *(const short8v*)(v2p + (size_t)node*64 + 32 + kg*8);
  float4v D[8];
#pragma unroll
  for (int n=0;n<8;++n) D[n] = (float4v){b2v[n],b2v[n],b2v[n],b2v[n]};

  for (int half=0; half<2; ++half){
    if (half) __syncthreads();
    for (int nt=0; nt<16; ++nt){
      int ntg = half*16 + nt;
      float bb = B1[ntg*16 + r16];
      float4v C = (float4v){bb,bb,bb,bb};
#pragma unroll
      for (int kc=0; kc<6; ++kc){
        C = __builtin_amdgcn_mfma_f32_16x16x32_bf16(A1[kc], W1h[(kc*32+ntg)*64+t], C, 0,0,0);
        C = __builtin_amdgcn_mfma_f32_16x16x32_bf16(A1[kc], W1l[(kc*32+ntg)*64+t], C, 0,0,0);
      }
#pragma unroll
      for (int r=0;r<4;++r)
        h1w[(kg*4+r)*260 + nt*16 + r16] = fmaxf(C[r], 0.f);
    }
    __syncthreads();
    short8v Ahi[8], Alo[8];
#pragma unroll
    for (int kc=0; kc<8; ++kc){
      const float* hp = h1w + r16*260 + kc*32 + kg*8;
      float4 x0 = *(const float4*)(hp);
      float4 x1 = *(const float4*)(hp+4);
      float vv[8] = {x0.x,x0.y,x0.z,x0.w,x1.x,x1.y,x1.z,x1.w};
#pragma unroll
      for (int j=0;j<8;++j){
        unsigned short hi = f2b(vv[j]);
        float rec = __builtin_bit_cast(float, (unsigned int)hi<<16);
        ((unsigned short*)&Ahi[kc])[j] = hi;
        ((unsigned short*)&Alo[kc])[j] = f2b(vv[j] - rec);
      }
    }
#pragma unroll
    for (int nt2=0; nt2<8; ++nt2){
#pragma unroll
      for (int kc=0; kc<8; ++kc){
        int kcg = half*8 + kc;
        short8v bh = W2h[(kcg*8+nt2)*64+t];
        D[nt2] = __builtin_amdgcn_mfma_f32_16x16x32_bf16(Ahi[kc], bh, D[nt2], 0,0,0);
        D[nt2] = __builtin_amdgcn_mfma_f32_16x16x32_bf16(Alo[kc], bh, D[nt2], 0,0,0);
        D[nt2] = __builtin_amdgcn_mfma_f32_16x16x32_bf16(Ahi[kc], W2l[(kcg*8+nt2)*64+t], D[nt2], 0,0,0);
      }
    }
  }
  float part[4] = {0.f,0.f,0.f,0.f};
#pragma unroll
  for (int n=0;n<8;++n){
#pragma unroll
    for (int r=0;r<4;++r) part[r] += fmaxf(D[n][r],0.f)*w3v[n];
  }
#pragma unroll
  for (int r=0;r<4;++r){
#pragma unroll
    for (int off=1; off<16; off<<=1) part[r] += __shfl_xor(part[r], off, 64);
  }
  if (act && r16==0){
#pragma unroll
    for (int r=0;r<4;++r){
      int node_o = g + kg*4 + r;
      float val = part[r] + bb3;
      if (md) ((bf16*)out)[node_o] = __float2bfloat16(val);
      else    ((float*)out)[node_o] = val;
    }
  }
}

extern "C" void kernel_launch(void* const* d_in, const int* in_sizes, int n_in,
                              void* d_out, int out_size, void* d_ws, size_t ws_size,
                              hipStream_t stream){
  const int* ei = (const int*)d_in[36];
  const int* src_c = ei;            // edge_index[0]: constraint ids
  const int* src_v = ei + NEDGE;    // edge_index[1]: variable ids

  char* ws = (char*)d_ws;
  float* ST = (float*)ws;                       // 4096 floats = 16 KB
  int* MODE = (int*)(ws + 16384);
  float* FBASE = (float*)(ws + 32768);
  CvtArgs ca;
  float* F[36];
  {
    int off = 0;
    for (int i=0;i<36;++i){
      ca.p[i] = d_in[i];
      ca.ofs[i] = off;
      F[i] = FBASE + off;
      off += in_sizes[i];
    }
    ca.ofs[36] = off;
  }
  unsigned short* W1Fb  = (unsigned short*)(ws + 7u*1024*1024);
  unsigned short* W2Fb  = W1Fb + 4*8192;
  unsigned short* OW1Fb = W2Fb + 4*4096;
  unsigned short* OW2Fb = OW1Fb + 4*8192;
  unsigned short* FW1H  = OW2Fb + 4*4096;
  unsigned short* FW1L  = FW1H + 98304;
  unsigned short* FW2H  = FW1L + 98304;
  unsigned short* FW2L  = FW2H + 65536;
  size_t o = 8u*1024*1024;
  float* AGG = (float*)(ws + o); o += (size_t)NCONS*64*sizeof(float);
  bf16* CFA = (bf16*)(ws + o); o += (size_t)NCONS*64*sizeof(bf16);
  bf16* CFB = (bf16*)(ws + o); o += (size_t)NCONS*64*sizeof(bf16);
  bf16* VF0 = (bf16*)(ws + o); o += (size_t)NVARS*64*sizeof(bf16);
  bf16* VF1 = (bf16*)(ws + o); o += (size_t)NVARS*64*sizeof(bf16);
  bf16* VF2 = (bf16*)(ws + o); o += (size_t)NVARS*64*sizeof(bf16);
  // CSR structures (~6 MB): counts, offsets, cursors, permutations
  int* CNTCI = (int*)(ws + o); o += (size_t)NCONS*sizeof(int);
  int* CNTVI = (int*)(ws + o); o += (size_t)NVARS*sizeof(int);
  int* OFFC  = (int*)(ws + o); o += (size_t)(NCONS+1)*sizeof(int);
  int* OFFV  = (int*)(ws + o); o += (size_t)(NVARS+1)*sizeof(int);
  int* CURC  = (int*)(ws + o); o += (size_t)NCONS*sizeof(int);
  int* CURV  = (int*)(ws + o); o += (size_t)NVARS*sizeof(int);
  int* PERMC = (int*)(ws + o); o += (size_t)NEDGE*sizeof(int);
  int* PERMV = (int*)(ws + o); o += (size_t)NEDGE*sizeof(int);
  // total ≈ 59 MB

  detect_k<<<1,64,0,stream>>>((const unsigned int*)d_in[0], MODE);
  convert_all_k<<<2048,256,0,stream>>>(ca, FBASE, MODE);
  frag_all_k<<<384,256,0,stream>>>(F[17], F[19], F[23], F[25], W1Fb, W2Fb, OW1Fb, OW2Fb);
  frag2_k<<<384,256,0,stream>>>(F[30], FW1H, FW1L, 32, 512, 98304);
  frag2_k<<<256,256,0,stream>>>(F[32], FW2H, FW2L, 8, 128, 65536);

  zero_k<<<8,256,0,stream>>>(ST, 4096);
  zero_k<<<128,256,0,stream>>>((float*)CNTCI, NCONS + NVARS);   // int 0 == float 0 bits
  hist_k<<<1024,256,0,stream>>>(ei, CNTCI, CNTVI);
  scan_k<<<1,1024,0,stream>>>(CNTCI, OFFC, CURC, NCONS);
  scan_k<<<1,1024,0,stream>>>(CNTVI, OFFV, CURV, NVARS);
  scat_k<<<1024,256,0,stream>>>(ei, CURC, CURV, PERMC, PERMV);

  col_stats_k<<<256,256,0,stream>>>(F[0], NCONS, 3, ST+0);
  col_stats_k<<<256,256,0,stream>>>(F[2], NVARS, 5, ST+6);
  col_stats_k<<<512,256,0,stream>>>(F[1], NEDGE, 1, ST+16);
  fin_input_k<<<1,64,0,stream>>>(ST, F[3], F[4], F[11], F[12], F[9], F[10]);
  embed_k<<<NCONS,64,0,stream>>>(F[0], 3, ST+18, ST+21, F[5], F[6], F[7], F[8], CFA, NCONS);
  embed_k<<<NVARS,64,0,stream>>>(F[2], 5, ST+24, ST+29, F[13], F[14], F[15], F[16], VF0, NVARS);

  const bf16* lefts[4]  = {VF0, CFB, VF1, CFA};
  const bf16* rights[4] = {CFA, VF0, CFB, VF1};
  bf16*       outs[4]   = {CFB, VF1, CFA, VF2};
  const int*  srcs[4]   = {src_v, src_c, src_v, src_c};
  const int*  perms[4]  = {PERMC, PERMV, PERMC, PERMV};
  const int*  offss[4]  = {OFFC, OFFV, OFFC, OFFV};

  for (int l=0; l<4; ++l){
    msg_csr_k<<<1024,256,0,stream>>>(lefts[l], rights[l], perms[l], srcs[l], F[1], ST+34,
                                     offss[l],
                                     W1Fb + l*8192, W2Fb + l*4096,
                                     F[18] + l*64,
                                     F[17] + (size_t)l*129*64 + 64*64,
                                     F[20] + l*64, AGG, NCONS);
    float* slot = ST + 36 + l*256;
    agg_stats_k<<<128,256,0,stream>>>(AGG, slot, NCONS);
    fin_bn_k<<<1,64,0,stream>>>(slot, F[21] + l*64, F[22] + l*64, (float)NCONS);
    node_mfma_k<<<512,256,0,stream>>>(AGG, rights[l], slot,
                                      OW1Fb + l*8192, OW2Fb + l*4096,
                                      F[24] + l*64, F[26] + l*64, outs[l], NCONS);
    if (l == 1 || l == 3){
      bf16* cfbuf = outs[l-1];
      bf16* vfbuf = outs[l];
      int ga = l-1, gb = l;
      float* gsA = ST + 36 + 1024 + ga*256;
      float* gsB = ST + 36 + 1024 + gb*256;
      gn_stats_k<<<128,256,0,stream>>>(cfbuf, gsA, NCONS);
      fin_gn_k<<<1,64,0,stream>>>(gsA, F[27]+ga*64, F[28]+ga*64, F[29]+ga*64, (float)NCONS);
      affine_k<<<1024,256,0,stream>>>(cfbuf, gsA, NCONS);
      gn_stats_k<<<128,256,0,stream>>>(vfbuf, gsB, NVARS);
      fin_gn_k<<<1,64,0,stream>>>(gsB, F[27]+gb*64, F[28]+gb*64, F[29]+gb*64, (float)NVARS);
      affine_k<<<1024,256,0,stream>>>(vfbuf, gsB, NVARS);
    }
  }
  final_mfma_k<<<782,256,0,stream>>>(VF0, VF1, VF2,
                                     FW1H, FW1L, FW2H, FW2L,
                                     F[31], F[33], F[34], F[35],
                                     d_out, NVARS, MODE);
}

// Round 11
// 1413.733 us; speedup vs baseline: 1.1271x; 1.1271x over previous
//
#include <hip/hip_runtime.h>
#include <hip/hip_bf16.h>

typedef __hip_bfloat16 bf16;
typedef __attribute__((ext_vector_type(8))) short short8v;
typedef __attribute__((ext_vector_type(4))) float float4v;

#define NCONS 50000
#define NVARS 50000
#define NEDGE 600000

__device__ __forceinline__ float b2f(const bf16 v){ return __bfloat162float(v); }
__device__ __forceinline__ float shflf(float v, int lane){ return __shfl(v, lane, 64); }
__device__ __forceinline__ unsigned short f2b(float v){
  return __builtin_bit_cast(unsigned short, __float2bfloat16(v));
}

// ---- input-dtype sniffer (bf16 pairs vs f32) ----
__global__ void detect_k(const unsigned int* __restrict__ x, int* __restrict__ mode){
  int t = threadIdx.x;
  int hits = 0;
  for (int i=0;i<4;++i){
    unsigned w = x[t*4+i];
    unsigned e = (w>>7)&0xFFu;
    if (e >= 0x70u && e <= 0x8Fu) hits++;
  }
  for (int off=32; off>0; off>>=1) hits += __shfl_down(hits, off);
  if (t==0) *mode = (hits > 128) ? 1 : 0;
}

// ---- convert ALL 36 float inputs to f32 workspace in one launch ----
struct CvtArgs { const void* p[36]; int ofs[37]; };
__global__ void convert_all_k(CvtArgs a, float* __restrict__ dst, const int* __restrict__ mode){
  int m = *mode;
  int i = blockIdx.x*blockDim.x + threadIdx.x;
  int stride = gridDim.x*blockDim.x;
  int total = a.ofs[36];
  for (; i<total; i+=stride){
    int s = 0;
#pragma unroll
    for (int k=1;k<36;++k) s += (i >= a.ofs[k]) ? 1 : 0;
    int off = i - a.ofs[s];
    float v;
    if (m) v = b2f(((const bf16*)a.p[s])[off]);
    else   v = ((const float*)a.p[s])[off];
    dst[i] = v;
  }
}

__global__ void zero_k(float* __restrict__ p, int n){
  int i = blockIdx.x*blockDim.x + threadIdx.x;
  int stride = gridDim.x*blockDim.x;
  for (; i<n; i+=stride) p[i] = 0.f;
}

// ---- CSR build: histogram, single-block scan (cnt becomes cursor), scatter ----
__global__ void hist_k(const int* __restrict__ ei, int* __restrict__ cntc, int* __restrict__ cntv){
  int i = blockIdx.x*blockDim.x + threadIdx.x;
  int stride = gridDim.x*blockDim.x;
  for (; i<2*NEDGE; i+=stride){
    int id = ei[i];
    if (i < NEDGE) atomicAdd(&cntc[id], 1);
    else           atomicAdd(&cntv[id], 1);
  }
}

__global__ void __launch_bounds__(1024) scan_k(int* __restrict__ cnt, int* __restrict__ offs, int n){
  __shared__ int part[1024];
  int t = threadIdx.x;
  int chunk = (n + 1023) >> 10;
  int b = t*chunk;
  int e = b + chunk; if (e > n) e = n;
  int s = 0;
  for (int i=b; i<e; ++i) s += cnt[i];
  part[t] = s;
  __syncthreads();
  for (int off=1; off<1024; off<<=1){
    int v = (t >= off) ? part[t-off] : 0;
    __syncthreads();
    part[t] += v;
    __syncthreads();
  }
  int run = (t==0) ? 0 : part[t-1];
  for (int i=b; i<e; ++i){
    int c = cnt[i];
    offs[i] = run; cnt[i] = run;   // cnt becomes cursor
    run += c;
  }
  if (t==1023) offs[n] = part[1023];
}

// scatter: write dst-sorted src ids and dst-sorted bf16 edge attrs directly
__global__ void scat_k(const int* __restrict__ ei, const float* __restrict__ ea,
                       int* __restrict__ curc, int* __restrict__ curv,
                       int* __restrict__ srtc, int* __restrict__ srtv,
                       bf16* __restrict__ eac, bf16* __restrict__ eav){
  int i = blockIdx.x*blockDim.x + threadIdx.x;
  int stride = gridDim.x*blockDim.x;
  for (; i<2*NEDGE; i+=stride){
    int id = ei[i];
    if (i < NEDGE){
      int p = atomicAdd(&curc[id],1);
      srtc[p] = ei[NEDGE+i];                 // variable endpoint
      eac[p] = __float2bfloat16(ea[i]);
    } else {
      int e = i - NEDGE;
      int p = atomicAdd(&curv[id],1);
      srtv[p] = ei[e];                       // constraint endpoint
      eav[p] = __float2bfloat16(ea[e]);
    }
  }
}

// ---- per-column sums / sumsq for BN folding ----
__global__ void col_stats_k(const float* __restrict__ x, int rows, int cols, float* __restrict__ sums){
  int tid = blockIdx.x*blockDim.x + threadIdx.x;
  int stride = gridDim.x*blockDim.x;
  float s[5], ss[5];
  for (int c=0;c<5;++c){ s[c]=0.f; ss[c]=0.f; }
  for (int r=tid; r<rows; r+=stride){
    for (int c=0;c<cols;++c){
      float v = x[r*cols+c];
      s[c]+=v; ss[c]+=v*v;
    }
  }
  for (int c=0;c<cols;++c){
    float a=s[c], b=ss[c];
    for (int off=32; off>0; off>>=1){ a+=__shfl_down(a,off); b+=__shfl_down(b,off); }
    if ((threadIdx.x & 63)==0){ atomicAdd(&sums[c],a); atomicAdd(&sums[cols+c],b); }
  }
}

// stats float layout in ST (floats): see round-5 comment (unchanged)
__global__ void fin_input_k(float* __restrict__ st,
                            const float* __restrict__ cw, const float* __restrict__ cb,
                            const float* __restrict__ vw, const float* __restrict__ vb,
                            const float* __restrict__ ew, const float* __restrict__ eb){
  int t = threadIdx.x;
  if (t < 3){
    float m = st[t]/(float)NCONS, q = st[3+t]/(float)NCONS;
    float A = rsqrtf(fmaxf(q - m*m, 0.f) + 1e-5f)*cw[t];
    st[18+t] = A; st[21+t] = cb[t] - m*A;
  } else if (t < 8){
    int c = t-3;
    float m = st[6+c]/(float)NVARS, q = st[11+c]/(float)NVARS;
    float A = rsqrtf(fmaxf(q - m*m, 0.f) + 1e-5f)*vw[c];
    st[24+c] = A; st[29+c] = vb[c] - m*A;
  } else if (t == 8){
    float m = st[16]/(float)NEDGE, q = st[17]/(float)NEDGE;
    float A = rsqrtf(fmaxf(q - m*m, 0.f) + 1e-5f)*ew[0];
    st[34] = A; st[35] = eb[0] - m*A;
  }
}

// ---- embedding: relu(relu(BN(x)@W1+b1)@W2+b2), block(64)=one node ----
__global__ void embed_k(const float* __restrict__ x, int cin,
                        const float* __restrict__ pA, const float* __restrict__ pB,
                        const float* __restrict__ W1, const float* __restrict__ b1,
                        const float* __restrict__ W2, const float* __restrict__ b2,
                        bf16* __restrict__ out, int nn){
  int n = blockIdx.x; if (n>=nn) return;
  int t = threadIdx.x;
  float acc = b1[t];
  for (int k=0;k<cin;++k){
    float xb = x[n*cin+k]*pA[k] + pB[k];
    acc += xb*W1[k*64+t];
  }
  float h1 = fmaxf(acc, 0.f);
  float acc2 = b2[t];
#pragma unroll
  for (int j=0;j<64;++j) acc2 += shflf(h1,j)*W2[j*64+t];
  out[n*64+t] = __float2bfloat16(fmaxf(acc2, 0.f));
}

// ---- all 16 conv-weight fragment jobs in one launch ----
__global__ void frag_all_k(const float* __restrict__ fmW1, const float* __restrict__ fmW2,
                           const float* __restrict__ omW1, const float* __restrict__ omW2,
                           unsigned short* __restrict__ W1Fb, unsigned short* __restrict__ W2Fb,
                           unsigned short* __restrict__ OW1Fb, unsigned short* __restrict__ OW2Fb){
  int i = blockIdx.x*blockDim.x + threadIdx.x;
  if (i >= 4*24576) return;
  int l = i / 24576, r = i % 24576;
  const float* src; unsigned short* dst; int e; int skip;
  if (r < 8192){       src = fmW1 + (size_t)l*129*64; dst = W1Fb  + l*8192; e = r;       skip = 64; }
  else if (r < 12288){ src = fmW2 + (size_t)l*64*64;  dst = W2Fb  + l*4096; e = r-8192;  skip = -1; }
  else if (r < 20480){ src = omW1 + (size_t)l*128*64; dst = OW1Fb + l*8192; e = r-12288; skip = -1; }
  else {               src = omW2 + (size_t)l*64*64;  dst = OW2Fb + l*4096; e = r-20480; skip = -1; }
  int j = e & 7, lane = (e>>3)&63, n = (e>>9)&3, kc = e>>11;
  int k = kc*32 + (lane>>4)*8 + j;
  int col = n*16 + (lane&15);
  int srcrow = (skip>=0 && k>=skip) ? k+1 : k;
  dst[e] = f2b(src[srcrow*64 + col]);
}

// ---- hi/lo fragmenter for final-MLP weights ----
__global__ void frag2_k(const float* __restrict__ Wsrc, unsigned short* __restrict__ Whi,
                        unsigned short* __restrict__ Wlo, int ntiles, int ncols, int tot){
  int i = blockIdx.x*blockDim.x + threadIdx.x;
  if (i>=tot) return;
  int j = i & 7, lane = (i>>3)&63, rem = i>>9;
  int nt = rem % ntiles, kc = rem / ntiles;
  int k = kc*32 + (lane>>4)*8 + j;
  int col = nt*16 + (lane&15);
  float w = Wsrc[k*ncols + col];
  unsigned short hi = f2b(w);
  float rec = __builtin_bit_cast(float, (unsigned int)hi << 16);
  Whi[i] = hi;
  Wlo[i] = f2b(w - rec);
}

// ---- CSR MFMA edge-message kernel + fused BN column stats.
// One wave per dst node; sorted src/ea (no perm indirection); no atomics on agg. ----
__global__ void __launch_bounds__(256) msg_csr_k(
    const bf16* __restrict__ left, const bf16* __restrict__ right,
    const int* __restrict__ srt, const bf16* __restrict__ eas,
    const float* __restrict__ est, const int* __restrict__ offs,
    const unsigned short* __restrict__ W1F, const unsigned short* __restrict__ W2F,
    const float* __restrict__ b1, const float* __restrict__ w1e, const float* __restrict__ b2,
    float* __restrict__ agg, float* __restrict__ slot, int nn)
{
  __shared__ __align__(16) unsigned short w1l[8192];
  __shared__ __align__(16) unsigned short w2l[4096];
  __shared__ __align__(16) unsigned short h1l[4][16*72];
  __shared__ float bstat[128];
  {
    const float4* s1 = (const float4*)W1F; float4* d1 = (float4*)w1l;
    for (int i=threadIdx.x; i<1024; i+=256) d1[i] = s1[i];
    const float4* s2 = (const float4*)W2F; float4* d2 = (float4*)w2l;
    for (int i=threadIdx.x; i<512; i+=256) d2[i] = s2[i];
    if (threadIdx.x < 128) bstat[threadIdx.x] = 0.f;
  }
  __syncthreads();
  const short8v* W1v = (const short8v*)w1l;
  const short8v* W2v = (const short8v*)w2l;
  const unsigned short* rgt = (const unsigned short*)right;
  const unsigned short* lft = (const unsigned short*)left;
  int t = threadIdx.x & 63;
  int wv = threadIdx.x >> 6;
  int gw = (blockIdx.x*blockDim.x + threadIdx.x) >> 6;
  int nw = (gridDim.x*blockDim.x) >> 6;
  int r16 = t & 15, kg = t >> 4;
  float eA = est[0], eB = est[1];
  float bb1[4], we[4], bb2[4];
#pragma unroll
  for (int n=0;n<4;++n){ bb1[n]=b1[n*16+r16]; we[n]=w1e[n*16+r16]; bb2[n]=b2[n*16+r16]; }
  unsigned short* h1w = &h1l[wv][0];
  float sacc[4] = {0.f,0.f,0.f,0.f}, ssacc[4] = {0.f,0.f,0.f,0.f};

  for (int node = gw; node < nn; node += nw){
    int beg = offs[node], end = offs[node+1];
    int deg = end - beg;
    float4v acc[4];
#pragma unroll
    for (int n=0;n<4;++n) acc[n] = (float4v){0.f,0.f,0.f,0.f};
    if (deg > 0){
      short8v rr0 = *(const short8v*)(rgt + (size_t)node*64 + kg*8);
      short8v rr1 = *(const short8v*)(rgt + (size_t)node*64 + 32 + kg*8);
      float4v crt[4];
#pragma unroll
      for (int n=0;n<4;++n) crt[n] = (float4v){bb1[n],bb1[n],bb1[n],bb1[n]};
#pragma unroll
      for (int n=0;n<4;++n){
        crt[n] = __builtin_amdgcn_mfma_f32_16x16x32_bf16(rr0, W1v[(0+n)*64+t], crt[n], 0,0,0);
        crt[n] = __builtin_amdgcn_mfma_f32_16x16x32_bf16(rr1, W1v[(4+n)*64+t], crt[n], 0,0,0);
      }
      for (int base = beg; base < end; base += 16){
        int idx = base + r16;
        int ic = idx < end ? idx : beg;
        int sI = srt[ic];
        float ef = b2f(eas[ic])*eA + eB;
        short8v al0 = *(const short8v*)(lft + (size_t)sI*64 + kg*8);
        short8v al1 = *(const short8v*)(lft + (size_t)sI*64 + 32 + kg*8);
        float efr[4];
#pragma unroll
        for (int r=0;r<4;++r) efr[r] = shflf(ef, kg*4+r);
        float4v c[4];
#pragma unroll
        for (int n=0;n<4;++n){
#pragma unroll
          for (int r=0;r<4;++r) c[n][r] = crt[n][r] + efr[r]*we[n];
        }
#pragma unroll
        for (int n=0;n<4;++n){
          c[n] = __builtin_amdgcn_mfma_f32_16x16x32_bf16(al0, W1v[( 8+n)*64+t], c[n], 0,0,0);
          c[n] = __builtin_amdgcn_mfma_f32_16x16x32_bf16(al1, W1v[(12+n)*64+t], c[n], 0,0,0);
        }
#pragma unroll
        for (int n=0;n<4;++n){
#pragma unroll
          for (int r=0;r<4;++r)
            h1w[(kg*4+r)*72 + n*16 + r16] = f2b(fmaxf(c[n][r], 0.f));
        }
        asm volatile("s_waitcnt lgkmcnt(0)" ::: "memory");
        __builtin_amdgcn_sched_barrier(0);
        short8v a20 = *(const short8v*)(h1w + r16*72 + kg*8);
        short8v a21 = *(const short8v*)(h1w + r16*72 + 32 + kg*8);
        float4v d[4];
#pragma unroll
        for (int n=0;n<4;++n) d[n] = (float4v){0.f,0.f,0.f,0.f};
#pragma unroll
        for (int n=0;n<4;++n){
          d[n] = __builtin_amdgcn_mfma_f32_16x16x32_bf16(a20, W2v[(0+n)*64+t], d[n], 0,0,0);
          d[n] = __builtin_amdgcn_mfma_f32_16x16x32_bf16(a21, W2v[(4+n)*64+t], d[n], 0,0,0);
        }
#pragma unroll
        for (int r=0;r<4;++r){
          float mrow = (base + kg*4 + r < end) ? 1.f : 0.f;
#pragma unroll
          for (int n=0;n<4;++n) acc[n][r] += mrow * d[n][r];
        }
      }
    }
    float tot[4];
#pragma unroll
    for (int n=0;n<4;++n){
      tot[n] = acc[n][0]+acc[n][1]+acc[n][2]+acc[n][3];
      tot[n] += __shfl_xor(tot[n], 16, 64);
      tot[n] += __shfl_xor(tot[n], 32, 64);
    }
    if (kg == 0){
      float inv = (deg>0) ? 1.f/(float)deg : 0.f;
#pragma unroll
      for (int n=0;n<4;++n){
        float val = (deg>0) ? tot[n]*inv + bb2[n] : 0.f;
        agg[(size_t)node*64 + n*16 + r16] = val;
        sacc[n] += val; ssacc[n] += val*val;
      }
    }
  }
  if (kg == 0){
#pragma unroll
    for (int n=0;n<4;++n){
      atomicAdd(&bstat[n*16+r16], sacc[n]);
      atomicAdd(&bstat[64+n*16+r16], ssacc[n]);
    }
  }
  __syncthreads();
  if (threadIdx.x < 128) atomicAdd(&slot[threadIdx.x], bstat[threadIdx.x]);
}

__global__ void fin_bn_k(float* __restrict__ slot, const float* __restrict__ w,
                         const float* __restrict__ b, float n){
  int c = threadIdx.x;
  float m = slot[c]/n, q = slot[64+c]/n;
  float rs = rsqrtf(fmaxf(q - m*m, 0.f) + 1e-5f) * w[c];
  slot[128+c] = rs;
  slot[192+c] = b[c] - m*rs;
}

// ---- MFMA node-output MLP + fused GraphNorm column stats. ----
__global__ void __launch_bounds__(256) node_mfma_k(
    const float* __restrict__ agg, const bf16* __restrict__ right,
    const float* __restrict__ slot,
    const unsigned short* __restrict__ W1F, const unsigned short* __restrict__ W2F,
    const float* __restrict__ b1, const float* __restrict__ b2,
    bf16* __restrict__ out, float* __restrict__ gslot, int nn)
{
  __shared__ __align__(16) unsigned short w1l[8192];
  __shared__ __align__(16) unsigned short w2l[4096];
  __shared__ __align__(16) unsigned short h1l[4][16*72];
  __shared__ float bstat[128];
  {
    const float4* s1 = (const float4*)W1F; float4* d1 = (float4*)w1l;
    for (int i=threadIdx.x; i<1024; i+=256) d1[i] = s1[i];
    const float4* s2 = (const float4*)W2F; float4* d2 = (float4*)w2l;
    for (int i=threadIdx.x; i<512; i+=256) d2[i] = s2[i];
    if (threadIdx.x < 128) bstat[threadIdx.x] = 0.f;
  }
  __syncthreads();
  const short8v* W1v = (const short8v*)w1l;
  const short8v* W2v = (const short8v*)w2l;
  const unsigned short* rgt = (const unsigned short*)right;
  int t = threadIdx.x & 63;
  int wv = threadIdx.x >> 6;
  int gw = (blockIdx.x*blockDim.x + threadIdx.x) >> 6;
  int nw = (gridDim.x*blockDim.x) >> 6;
  int r16 = t & 15, kg = t >> 4;
  float pA0[8], pB0[8], pA1[8], pB1[8];
#pragma unroll
  for (int j=0;j<8;++j){
    pA0[j]=slot[128+kg*8+j]; pB0[j]=slot[192+kg*8+j];
    pA1[j]=slot[160+kg*8+j]; pB1[j]=slot[224+kg*8+j];
  }
  float bb1[4], bb2[4];
#pragma unroll
  for (int n=0;n<4;++n){ bb1[n]=b1[n*16+r16]; bb2[n]=b2[n*16+r16]; }
  unsigned short* h1w = &h1l[wv][0];
  float sacc[4] = {0.f,0.f,0.f,0.f}, ssacc[4] = {0.f,0.f,0.f,0.f};

  for (int g = gw*16; g < nn; g += nw*16){
    int node = g + r16;
    const float* ag = agg + (size_t)node*64;
    float4 f0 = *(const float4*)(ag + kg*8);
    float4 f1 = *(const float4*)(ag + kg*8 + 4);
    float4 f2 = *(const float4*)(ag + 32 + kg*8);
    float4 f3 = *(const float4*)(ag + 32 + kg*8 + 4);
    float v0[8] = {f0.x,f0.y,f0.z,f0.w,f1.x,f1.y,f1.z,f1.w};
    float v1[8] = {f2.x,f2.y,f2.z,f2.w,f3.x,f3.y,f3.z,f3.w};
    short8v ap0, ap1;
#pragma unroll
    for (int j=0;j<8;++j){
      ((unsigned short*)&ap0)[j] = f2b(v0[j]*pA0[j] + pB0[j]);
      ((unsigned short*)&ap1)[j] = f2b(v1[j]*pA1[j] + pB1[j]);
    }
    short8v ar0 = *(const short8v*)(rgt + (size_t)node*64 + kg*8);
    short8v ar1 = *(const short8v*)(rgt + (size_t)node*64 + 32 + kg*8);
    float4v c[4];
#pragma unroll
    for (int n=0;n<4;++n) c[n] = (float4v){bb1[n],bb1[n],bb1[n],bb1[n]};
#pragma unroll
    for (int n=0;n<4;++n){
      c[n] = __builtin_amdgcn_mfma_f32_16x16x32_bf16(ap0, W1v[( 0+n)*64+t], c[n], 0,0,0);
      c[n] = __builtin_amdgcn_mfma_f32_16x16x32_bf16(ap1, W1v[( 4+n)*64+t], c[n], 0,0,0);
      c[n] = __builtin_amdgcn_mfma_f32_16x16x32_bf16(ar0, W1v[( 8+n)*64+t], c[n], 0,0,0);
      c[n] = __builtin_amdgcn_mfma_f32_16x16x32_bf16(ar1, W1v[(12+n)*64+t], c[n], 0,0,0);
    }
#pragma unroll
    for (int n=0;n<4;++n){
#pragma unroll
      for (int r=0;r<4;++r)
        h1w[(kg*4+r)*72 + n*16 + r16] = f2b(fmaxf(c[n][r], 0.f));
    }
    asm volatile("s_waitcnt lgkmcnt(0)" ::: "memory");
    __builtin_amdgcn_sched_barrier(0);
    short8v a20 = *(const short8v*)(h1w + r16*72 + kg*8);
    short8v a21 = *(const short8v*)(h1w + r16*72 + 32 + kg*8);
    float4v d[4];
#pragma unroll
    for (int n=0;n<4;++n) d[n] = (float4v){bb2[n],bb2[n],bb2[n],bb2[n]};
#pragma unroll
    for (int n=0;n<4;++n){
      d[n] = __builtin_amdgcn_mfma_f32_16x16x32_bf16(a20, W2v[(0+n)*64+t], d[n], 0,0,0);
      d[n] = __builtin_amdgcn_mfma_f32_16x16x32_bf16(a21, W2v[(4+n)*64+t], d[n], 0,0,0);
    }
    unsigned short* op = (unsigned short*)out;
#pragma unroll
    for (int r=0;r<4;++r){
      size_t base = (size_t)(g + kg*4 + r)*64 + r16;
#pragma unroll
      for (int n=0;n<4;++n){
        float val = d[n][r];
        op[base + n*16] = f2b(val);
        sacc[n] += val; ssacc[n] += val*val;
      }
    }
  }
#pragma unroll
  for (int n=0;n<4;++n){
    atomicAdd(&bstat[n*16+r16], sacc[n]);
    atomicAdd(&bstat[64+n*16+r16], ssacc[n]);
  }
  __syncthreads();
  if (threadIdx.x < 128) atomicAdd(&gslot[threadIdx.x], bstat[threadIdx.x]);
}

// ---- merged graphnorm finalize (both slots) and apply (both buffers) ----
__global__ void fin_gn2_k(float* __restrict__ sA, float* __restrict__ sB,
                          const float* __restrict__ w, const float* __restrict__ b,
                          const float* __restrict__ al, int ga, int gb, float n){
  int t = threadIdx.x; if (t >= 128) return;
  float* slot = (t < 64) ? sA : sB;
  int g = (t < 64) ? ga : gb;
  int c = t & 63;
  float m = slot[c]/n, q = slot[64+c]/n;
  float a = al[g*64+c];
  float var = q - 2.f*a*m*m + a*a*m*m;
  float A = rsqrtf(fmaxf(var, 0.f) + 1e-5f) * w[g*64+c];
  slot[128+c] = A;
  slot[192+c] = b[g*64+c] - a*m*A;
}

__global__ void affine2_k(bf16* __restrict__ x1, const float* __restrict__ s1,
                          bf16* __restrict__ x2, const float* __restrict__ s2, int nn){
  int i = blockIdx.x*blockDim.x + threadIdx.x;
  int stride = gridDim.x*blockDim.x;
  int tot = nn*64;
  for (; i<2*tot; i+=stride){
    if (i < tot){
      int c = i & 63;
      x1[i] = __float2bfloat16(b2f(x1[i])*s1[128+c] + s1[192+c]);
    } else {
      int j = i - tot;
      int c = j & 63;
      x2[j] = __float2bfloat16(b2f(x2[j])*s2[128+c] + s2[192+c]);
    }
  }
}

// ---- MFMA final MLP, race-free (one 16-node tile per wave, __syncthreads) ----
__global__ void __launch_bounds__(256) final_mfma_k(
    const bf16* __restrict__ vf0, const bf16* __restrict__ vf1, const bf16* __restrict__ vf2,
    const unsigned short* __restrict__ W1hi, const unsigned short* __restrict__ W1lo,
    const unsigned short* __restrict__ W2hi, const unsigned short* __restrict__ W2lo,
    const float* __restrict__ B1, const float* __restrict__ B2,
    const float* __restrict__ W3, const float* __restrict__ B3,
    void* __restrict__ out, int nn, const int* __restrict__ mode)
{
  __shared__ float h1l[4][16*260];
  const short8v* W1h = (const short8v*)W1hi;
  const short8v* W1l = (const short8v*)W1lo;
  const short8v* W2h = (const short8v*)W2hi;
  const short8v* W2l = (const short8v*)W2lo;
  const unsigned short* v0p = (const unsigned short*)vf0;
  const unsigned short* v1p = (const unsigned short*)vf1;
  const unsigned short* v2p = (const unsigned short*)vf2;
  int t = threadIdx.x & 63;
  int wv = threadIdx.x >> 6;
  int r16 = t & 15, kg = t >> 4;
  int tile = blockIdx.x*4 + wv;
  bool act = (tile*16 < nn);
  int g = act ? tile*16 : 0;
  float* h1w = &h1l[wv][0];
  float b2v[8], w3v[8];
#pragma unroll
  for (int n=0;n<8;++n){ b2v[n] = B2[n*16+r16]; w3v[n] = W3[n*16+r16]; }
  float bb3 = B3[0];
  int md = *mode;

  int node = g + r16;
  short8v A1[6];
  A1[0] = *(const short8v*)(v0p + (size_t)node*64 + kg*8);
  A1[1] = *(const short8v*)(v0p + (size_t)node*64 + 32 + kg*8);
  A1[2] = *(const short8v*)(v1p + (size_t)node*64 + kg*8);
  A1[3] = *(const short8v*)(v1p + (size_t)node*64 + 32 + kg*8);
  A1[4] = *(const short8v*)(v2p + (size_t)node*64 + kg*8);
  A1[5] = *(const short8v*)(v2p + (size_t)node*64 + 32 + kg*8);
  float4v D[8];
#pragma unroll
  for (int n=0;n<8;++n) D[n] = (float4v){b2v[n],b2v[n],b2v[n],b2v[n]};

  for (int half=0; half<2; ++half){
    if (half) __syncthreads();
    for (int nt=0; nt<16; ++nt){
      int ntg = half*16 + nt;
      float bb = B1[ntg*16 + r16];
      float4v C = (float4v){bb,bb,bb,bb};
#pragma unroll
      for (int kc=0; kc<6; ++kc){
        C = __builtin_amdgcn_mfma_f32_16x16x32_bf16(A1[kc], W1h[(kc*32+ntg)*64+t], C, 0,0,0);
        C = __builtin_amdgcn_mfma_f32_16x16x32_bf16(A1[kc], W1l[(kc*32+ntg)*64+t], C, 0,0,0);
      }
#pragma unroll
      for (int r=0;r<4;++r)
        h1w[(kg*4+r)*260 + nt*16 + r16] = fmaxf(C[r], 0.f);
    }
    __syncthreads();
    short8v Ahi[8], Alo[8];
#pragma unroll
    for (int kc=0; kc<8; ++kc){
      const float* hp = h1w + r16*260 + kc*32 + kg*8;
      float4 x0 = *(const float4*)(hp);
      float4 x1 = *(const float4*)(hp+4);
      float vv[8] = {x0.x,x0.y,x0.z,x0.w,x1.x,x1.y,x1.z,x1.w};
#pragma unroll
      for (int j=0;j<8;++j){
        unsigned short hi = f2b(vv[j]);
        float rec = __builtin_bit_cast(float, (unsigned int)hi<<16);
        ((unsigned short*)&Ahi[kc])[j] = hi;
        ((unsigned short*)&Alo[kc])[j] = f2b(vv[j] - rec);
      }
    }
#pragma unroll
    for (int nt2=0; nt2<8; ++nt2){
#pragma unroll
      for (int kc=0; kc<8; ++kc){
        int kcg = half*8 + kc;
        short8v bh = W2h[(kcg*8+nt2)*64+t];
        D[nt2] = __builtin_amdgcn_mfma_f32_16x16x32_bf16(Ahi[kc], bh, D[nt2], 0,0,0);
        D[nt2] = __builtin_amdgcn_mfma_f32_16x16x32_bf16(Alo[kc], bh, D[nt2], 0,0,0);
        D[nt2] = __builtin_amdgcn_mfma_f32_16x16x32_bf16(Ahi[kc], W2l[(kcg*8+nt2)*64+t], D[nt2], 0,0,0);
      }
    }
  }
  float part[4] = {0.f,0.f,0.f,0.f};
#pragma unroll
  for (int n=0;n<8;++n){
#pragma unroll
    for (int r=0;r<4;++r) part[r] += fmaxf(D[n][r],0.f)*w3v[n];
  }
#pragma unroll
  for (int r=0;r<4;++r){
#pragma unroll
    for (int off=1; off<16; off<<=1) part[r] += __shfl_xor(part[r], off, 64);
  }
  if (act && r16==0){
#pragma unroll
    for (int r=0;r<4;++r){
      int node_o = g + kg*4 + r;
      float val = part[r] + bb3;
      if (md) ((bf16*)out)[node_o] = __float2bfloat16(val);
      else    ((float*)out)[node_o] = val;
    }
  }
}

extern "C" void kernel_launch(void* const* d_in, const int* in_sizes, int n_in,
                              void* d_out, int out_size, void* d_ws, size_t ws_size,
                              hipStream_t stream){
  const int* ei = (const int*)d_in[36];

  char* ws = (char*)d_ws;
  float* ST = (float*)ws;                       // 4096 floats = 16 KB
  int* MODE = (int*)(ws + 16384);
  float* FBASE = (float*)(ws + 32768);
  CvtArgs ca;
  float* F[36];
  {
    int off = 0;
    for (int i=0;i<36;++i){
      ca.p[i] = d_in[i];
      ca.ofs[i] = off;
      F[i] = FBASE + off;
      off += in_sizes[i];
    }
    ca.ofs[36] = off;
  }
  unsigned short* W1Fb  = (unsigned short*)(ws + 7u*1024*1024);
  unsigned short* W2Fb  = W1Fb + 4*8192;
  unsigned short* OW1Fb = W2Fb + 4*4096;
  unsigned short* OW2Fb = OW1Fb + 4*8192;
  unsigned short* FW1H  = OW2Fb + 4*4096;
  unsigned short* FW1L  = FW1H + 98304;
  unsigned short* FW2H  = FW1L + 98304;
  unsigned short* FW2L  = FW2H + 65536;
  size_t o = 8u*1024*1024;
  float* AGG = (float*)(ws + o); o += (size_t)NCONS*64*sizeof(float);
  bf16* CFA = (bf16*)(ws + o); o += (size_t)NCONS*64*sizeof(bf16);
  bf16* CFB = (bf16*)(ws + o); o += (size_t)NCONS*64*sizeof(bf16);
  bf16* VF0 = (bf16*)(ws + o); o += (size_t)NVARS*64*sizeof(bf16);
  bf16* VF1 = (bf16*)(ws + o); o += (size_t)NVARS*64*sizeof(bf16);
  bf16* VF2 = (bf16*)(ws + o); o += (size_t)NVARS*64*sizeof(bf16);
  // CSR structures: counts(->cursors), offsets, sorted src ids, sorted ea bf16
  int* CNTCI = (int*)(ws + o); o += (size_t)NCONS*sizeof(int);
  int* CNTVI = (int*)(ws + o); o += (size_t)NVARS*sizeof(int);
  int* OFFC  = (int*)(ws + o); o += (size_t)(NCONS+1)*sizeof(int);
  int* OFFV  = (int*)(ws + o); o += (size_t)(NVARS+1)*sizeof(int);
  int* SRTC  = (int*)(ws + o); o += (size_t)NEDGE*sizeof(int);
  int* SRTV  = (int*)(ws + o); o += (size_t)NEDGE*sizeof(int);
  bf16* EAC  = (bf16*)(ws + o); o += (size_t)NEDGE*sizeof(bf16);
  bf16* EAV  = (bf16*)(ws + o); o += (size_t)NEDGE*sizeof(bf16);
  // total ≈ 61.5 MB

  detect_k<<<1,64,0,stream>>>((const unsigned int*)d_in[0], MODE);
  convert_all_k<<<2048,256,0,stream>>>(ca, FBASE, MODE);
  frag_all_k<<<384,256,0,stream>>>(F[17], F[19], F[23], F[25], W1Fb, W2Fb, OW1Fb, OW2Fb);
  frag2_k<<<384,256,0,stream>>>(F[30], FW1H, FW1L, 32, 512, 98304);
  frag2_k<<<256,256,0,stream>>>(F[32], FW2H, FW2L, 8, 128, 65536);

  zero_k<<<8,256,0,stream>>>(ST, 4096);
  zero_k<<<128,256,0,stream>>>((float*)CNTCI, NCONS + NVARS);
  hist_k<<<1024,256,0,stream>>>(ei, CNTCI, CNTVI);
  scan_k<<<1,1024,0,stream>>>(CNTCI, OFFC, NCONS);
  scan_k<<<1,1024,0,stream>>>(CNTVI, OFFV, NVARS);
  scat_k<<<1024,256,0,stream>>>(ei, F[1], CNTCI, CNTVI, SRTC, SRTV, EAC, EAV);

  col_stats_k<<<256,256,0,stream>>>(F[0], NCONS, 3, ST+0);
  col_stats_k<<<256,256,0,stream>>>(F[2], NVARS, 5, ST+6);
  col_stats_k<<<512,256,0,stream>>>(F[1], NEDGE, 1, ST+16);
  fin_input_k<<<1,64,0,stream>>>(ST, F[3], F[4], F[11], F[12], F[9], F[10]);
  embed_k<<<NCONS,64,0,stream>>>(F[0], 3, ST+18, ST+21, F[5], F[6], F[7], F[8], CFA, NCONS);
  embed_k<<<NVARS,64,0,stream>>>(F[2], 5, ST+24, ST+29, F[13], F[14], F[15], F[16], VF0, NVARS);

  const bf16* lefts[4]  = {VF0, CFB, VF1, CFA};
  const bf16* rights[4] = {CFA, VF0, CFB, VF1};
  bf16*       outs[4]   = {CFB, VF1, CFA, VF2};
  const int*  srts[4]   = {SRTC, SRTV, SRTC, SRTV};
  const bf16* eass[4]   = {EAC, EAV, EAC, EAV};
  const int*  offss[4]  = {OFFC, OFFV, OFFC, OFFV};

  for (int l=0; l<4; ++l){
    float* slot = ST + 36 + l*256;
    float* gslot = ST + 36 + 1024 + l*256;
    msg_csr_k<<<1024,256,0,stream>>>(lefts[l], rights[l], srts[l], eass[l], ST+34,
                                     offss[l],
                                     W1Fb + l*8192, W2Fb + l*4096,
                                     F[18] + l*64,
                                     F[17] + (size_t)l*129*64 + 64*64,
                                     F[20] + l*64, AGG, slot, NCONS);
    fin_bn_k<<<1,64,0,stream>>>(slot, F[21] + l*64, F[22] + l*64, (float)NCONS);
    node_mfma_k<<<782,256,0,stream>>>(AGG, rights[l], slot,
                                      OW1Fb + l*8192, OW2Fb + l*4096,
                                      F[24] + l*64, F[26] + l*64, outs[l], gslot, NCONS);
    if (l == 1 || l == 3){
      bf16* cfbuf = outs[l-1];
      bf16* vfbuf = outs[l];
      int ga = l-1, gb = l;
      float* gsA = ST + 36 + 1024 + ga*256;
      float* gsB = ST + 36 + 1024 + gb*256;
      fin_gn2_k<<<1,128,0,stream>>>(gsA, gsB, F[27], F[28], F[29], ga, gb, 50000.f);
      affine2_k<<<1024,256,0,stream>>>(cfbuf, gsA, vfbuf, gsB, NCONS);
    }
  }
  final_mfma_k<<<782,256,0,stream>>>(VF0, VF1, VF2,
                                     FW1H, FW1L, FW2H, FW2L,
                                     F[31], F[33], F[34], F[35],
                                     d_out, NVARS, MODE);
}